// Round 2
// baseline (274.359 us; speedup 1.0000x reference)
//
#include <hip/hip_runtime.h>
#include <math.h>

#define TILE 32
#define HALO 5
#define IN_T 42              // TILE + 2*HALO
#define HWDIM 512
#define NPLANES 48           // B*C = 16*3
#define NPIX (16ull*3ull*512ull*512ull)

struct GW { float g[11]; };

__global__ void ssim_zero_ws(float* ws) { ws[0] = 0.0f; }

__global__ void ssim_finalize(const float* __restrict__ ws, float* __restrict__ out) {
    out[0] = 1.0f - ws[0] * (1.0f / (float)NPIX);
}

__global__ __launch_bounds__(256) void ssim_main(
    const float* __restrict__ img1, const float* __restrict__ img2,
    float* __restrict__ ws, GW gw)
{
    __shared__ float sx[IN_T][IN_T];
    __shared__ float sy[IN_T][IN_T];
    __shared__ float s_int[5][IN_T][TILE];   // hx, hy, hxx, hyy, hxy (horizontally convolved)
    __shared__ float s_red[4];

    const int tid = threadIdx.x;
    const int tx = blockIdx.x, ty = blockIdx.y, plane = blockIdx.z;
    const float* __restrict__ p1 = img1 + (size_t)plane * (HWDIM * HWDIM);
    const float* __restrict__ p2 = img2 + (size_t)plane * (HWDIM * HWDIM);
    const int gy0 = ty * TILE - HALO;
    const int gx0 = tx * TILE - HALO;

    // ---- stage input tiles (zero-padded, matching reference zero padding) ----
    for (int idx = tid; idx < IN_T * IN_T; idx += 256) {
        const int r = idx / IN_T;
        const int c = idx - r * IN_T;
        const int gy = gy0 + r, gx = gx0 + c;
        float v1 = 0.0f, v2 = 0.0f;
        if (gy >= 0 && gy < HWDIM && gx >= 0 && gx < HWDIM) {
            const int off = gy * HWDIM + gx;
            v1 = p1[off];
            v2 = p2[off];
        }
        sx[r][c] = v1;
        sy[r][c] = v2;
    }
    __syncthreads();

    // ---- horizontal 11-tap pass: 42 rows x 32 cols, 5 quantities ----
    for (int idx = tid; idx < IN_T * TILE; idx += 256) {
        const int r = idx >> 5;        // 0..41
        const int c = idx & 31;        // 0..31
        float a0 = 0.f, a1 = 0.f, a2 = 0.f, a3 = 0.f, a4 = 0.f;
#pragma unroll
        for (int k = 0; k < 11; ++k) {
            const float xv = sx[r][c + k];
            const float yv = sy[r][c + k];
            const float g  = gw.g[k];
            const float gx_ = g * xv;
            const float gy_ = g * yv;
            a0 += gx_;
            a1 += gy_;
            a2 = fmaf(gx_, xv, a2);
            a3 = fmaf(gy_, yv, a3);
            a4 = fmaf(gx_, yv, a4);
        }
        s_int[0][r][c] = a0;
        s_int[1][r][c] = a1;
        s_int[2][r][c] = a2;
        s_int[3][r][c] = a3;
        s_int[4][r][c] = a4;
    }
    __syncthreads();

    // ---- vertical 11-tap pass, 4 output rows per thread (sliding window) ----
    const int c  = tid & 31;            // column 0..31
    const int r0 = (tid >> 5) * 4;      // base output row: 0,4,...,28
    float acc[5][4];
#pragma unroll
    for (int q = 0; q < 5; ++q)
#pragma unroll
        for (int o = 0; o < 4; ++o) acc[q][o] = 0.0f;

#pragma unroll
    for (int j = 0; j < 14; ++j) {
        float v[5];
#pragma unroll
        for (int q = 0; q < 5; ++q) v[q] = s_int[q][r0 + j][c];
#pragma unroll
        for (int o = 0; o < 4; ++o) {
            const int k = j - o;
            if (k >= 0 && k < 11) {
                const float g = gw.g[k];
#pragma unroll
                for (int q = 0; q < 5; ++q) acc[q][o] = fmaf(g, v[q], acc[q][o]);
            }
        }
    }

    // ---- SSIM map + local sum ----
    const float C1 = 0.01f * 0.01f;
    const float C2 = 0.03f * 0.03f;
    float lsum = 0.0f;
#pragma unroll
    for (int o = 0; o < 4; ++o) {
        const float mu1 = acc[0][o];
        const float mu2 = acc[1][o];
        const float mu1_sq = mu1 * mu1;
        const float mu2_sq = mu2 * mu2;
        const float mu1_mu2 = mu1 * mu2;
        const float sigma1_sq = acc[2][o] - mu1_sq;
        const float sigma2_sq = acc[3][o] - mu2_sq;
        const float sigma12   = acc[4][o] - mu1_mu2;
        const float num = (2.0f * mu1_mu2 + C1) * (2.0f * sigma12 + C2);
        const float den = (mu1_sq + mu2_sq + C1) * (sigma1_sq + sigma2_sq + C2);
        lsum += num / den;
    }

    // ---- reduction: wave shuffle -> LDS -> one atomicAdd per block ----
#pragma unroll
    for (int off = 32; off > 0; off >>= 1)
        lsum += __shfl_down(lsum, off, 64);
    if ((tid & 63) == 0) s_red[tid >> 6] = lsum;
    __syncthreads();
    if (tid == 0) {
        atomicAdd(ws, s_red[0] + s_red[1] + s_red[2] + s_red[3]);
    }
}

extern "C" void kernel_launch(void* const* d_in, const int* in_sizes, int n_in,
                              void* d_out, int out_size, void* d_ws, size_t ws_size,
                              hipStream_t stream) {
    const float* img1 = (const float*)d_in[0];
    const float* img2 = (const float*)d_in[1];
    float* out = (float*)d_out;
    float* wsf = (float*)d_ws;

    // Gaussian window, computed exactly as the reference (float64 -> float32)
    GW gw;
    {
        double g[11], s = 0.0;
        for (int i = 0; i < 11; ++i) {
            const double d = (double)(i - 5);
            g[i] = exp(-(d * d) / (2.0 * 1.5 * 1.5));
            s += g[i];
        }
        for (int i = 0; i < 11; ++i) gw.g[i] = (float)(g[i] / s);
    }

    ssim_zero_ws<<<1, 1, 0, stream>>>(wsf);
    dim3 grid(HWDIM / TILE, HWDIM / TILE, NPLANES);   // 16 x 16 x 48
    ssim_main<<<grid, 256, 0, stream>>>(img1, img2, wsf, gw);
    ssim_finalize<<<1, 1, 0, stream>>>(wsf, out);
}

// Round 3
// 191.881 us; speedup vs baseline: 1.4298x; 1.4298x over previous
//
#include <hip/hip_runtime.h>
#include <math.h>

#define TILE 32
#define HALO 5
#define IN_T 42              // TILE + 2*HALO rows
#define ROWP 44              // padded row length (44*4B = 176B, multiple of 16B)
#define HWDIM 512
#define NPLANES 48           // B*C = 16*3
#define NBLK (16*16*48)      // grid blocks = 12288
#define NPIX (16ull*3ull*512ull*512ull)

struct GW { float g[11]; };

// ---------------- final reduce: 12288 partials -> 1 - mean ----------------
__global__ __launch_bounds__(256) void ssim_reduce(
    const float* __restrict__ partial, float* __restrict__ out)
{
    __shared__ float s_red[4];
    const int tid = threadIdx.x;
    float s = 0.0f;
#pragma unroll
    for (int k = 0; k < NBLK / 256; ++k) s += partial[tid + k * 256];
#pragma unroll
    for (int off = 32; off > 0; off >>= 1) s += __shfl_down(s, off, 64);
    if ((tid & 63) == 0) s_red[tid >> 6] = s;
    __syncthreads();
    if (tid == 0) {
        const float tot = s_red[0] + s_red[1] + s_red[2] + s_red[3];
        out[0] = 1.0f - tot * (1.0f / (float)NPIX);
    }
}

// ---------------- main fused SSIM kernel ----------------
__global__ __launch_bounds__(256, 4) void ssim_main(
    const float* __restrict__ img1, const float* __restrict__ img2,
    float* __restrict__ partial, GW gw)
{
    __shared__ alignas(16) float sx[IN_T][ROWP];
    __shared__ alignas(16) float sy[IN_T][ROWP];
    __shared__ float4 s_int[IN_T][TILE + 1];   // (mu1h, mu2h, uuh, vvh); +1 pad -> conflict-free
    __shared__ float s_red[4];

    const int tid = threadIdx.x;
    const int tx = blockIdx.x, ty = blockIdx.y, plane = blockIdx.z;
    const float* __restrict__ p1 = img1 + (size_t)plane * (HWDIM * HWDIM);
    const float* __restrict__ p2 = img2 + (size_t)plane * (HWDIM * HWDIM);
    const int gy0 = ty * TILE - HALO;
    const int gx0 = tx * TILE - HALO;

    // ---- stage raw tiles (zero-padded; pad columns also written 0) ----
    for (int idx = tid; idx < IN_T * ROWP; idx += 256) {
        const int r = idx / ROWP;
        const int c = idx - r * ROWP;
        const int gy = gy0 + r, gx = gx0 + c;
        float v1 = 0.0f, v2 = 0.0f;
        if (gy >= 0 && gy < HWDIM && gx >= 0 && gx < HWDIM) {
            const int off = gy * HWDIM + gx;
            v1 = p1[off];
            v2 = p2[off];
        }
        sx[r][c] = v1;
        sy[r][c] = v2;
    }
    __syncthreads();

    // ---- horizontal 11-tap pass: 42 rows x 8 groups of 4 outputs = 336 items ----
    // quantities: conv(x), conv(y), conv((x+y)^2), conv((x-y)^2)
    for (int item = tid; item < IN_T * 8; item += 256) {
        const int r = item >> 3;          // 0..41
        const int g8 = item & 7;          // 0..7
        const int c0 = g8 * 4;            // output col base 0,4,...,28

        const float4* rowx = reinterpret_cast<const float4*>(&sx[r][0]);
        const float4* rowy = reinterpret_cast<const float4*>(&sy[r][0]);
        float x[16], y[16];
        *reinterpret_cast<float4*>(&x[0])  = rowx[g8 + 0];
        *reinterpret_cast<float4*>(&x[4])  = rowx[g8 + 1];
        *reinterpret_cast<float4*>(&x[8])  = rowx[g8 + 2];
        *reinterpret_cast<float4*>(&x[12]) = rowx[g8 + 3];
        *reinterpret_cast<float4*>(&y[0])  = rowy[g8 + 0];
        *reinterpret_cast<float4*>(&y[4])  = rowy[g8 + 1];
        *reinterpret_cast<float4*>(&y[8])  = rowy[g8 + 2];
        *reinterpret_cast<float4*>(&y[12]) = rowy[g8 + 3];

        float a[4][4];
#pragma unroll
        for (int o = 0; o < 4; ++o)
#pragma unroll
            for (int q = 0; q < 4; ++q) a[o][q] = 0.0f;

#pragma unroll
        for (int e = 0; e < 14; ++e) {
            const float xe = x[e], ye = y[e];
            const float u = xe + ye, v = xe - ye;
            const float uu = u * u, vv = v * v;
#pragma unroll
            for (int o = 0; o < 4; ++o) {
                const int k = e - o;
                if (k >= 0 && k < 11) {
                    const float g = gw.g[k];
                    a[o][0] = fmaf(g, xe, a[o][0]);
                    a[o][1] = fmaf(g, ye, a[o][1]);
                    a[o][2] = fmaf(g, uu, a[o][2]);
                    a[o][3] = fmaf(g, vv, a[o][3]);
                }
            }
        }
#pragma unroll
        for (int o = 0; o < 4; ++o)
            s_int[r][c0 + o] = make_float4(a[o][0], a[o][1], a[o][2], a[o][3]);
    }
    __syncthreads();

    // ---- vertical 11-tap pass: thread = (col, 4 output rows), sliding window ----
    const int c  = tid & 31;
    const int r0 = (tid >> 5) * 4;       // 0,4,...,28
    float acc[4][4];                     // [output o][quantity q]
#pragma unroll
    for (int o = 0; o < 4; ++o)
#pragma unroll
        for (int q = 0; q < 4; ++q) acc[o][q] = 0.0f;

#pragma unroll
    for (int j = 0; j < 14; ++j) {
        const float4 v = s_int[r0 + j][c];
#pragma unroll
        for (int o = 0; o < 4; ++o) {
            const int k = j - o;
            if (k >= 0 && k < 11) {
                const float g = gw.g[k];
                acc[o][0] = fmaf(g, v.x, acc[o][0]);
                acc[o][1] = fmaf(g, v.y, acc[o][1]);
                acc[o][2] = fmaf(g, v.z, acc[o][2]);
                acc[o][3] = fmaf(g, v.w, acc[o][3]);
            }
        }
    }

    // ---- SSIM map + local sum ----
    const float C1 = 0.01f * 0.01f;
    const float C2 = 0.03f * 0.03f;
    float lsum = 0.0f;
#pragma unroll
    for (int o = 0; o < 4; ++o) {
        const float mu1 = acc[o][0];
        const float mu2 = acc[o][1];
        const float s_uu = acc[o][2];
        const float s_vv = acc[o][3];
        const float mu1_sq = mu1 * mu1;
        const float mu2_sq = mu2 * mu2;
        const float mu1_mu2 = mu1 * mu2;
        const float sigma12 = (s_uu - s_vv) * 0.25f - mu1_mu2;
        const float sigsum  = (s_uu + s_vv) * 0.5f - mu1_sq - mu2_sq;
        const float num = (2.0f * mu1_mu2 + C1) * (2.0f * sigma12 + C2);
        const float den = (mu1_sq + mu2_sq + C1) * (sigsum + C2);
        lsum += num / den;
    }

    // ---- reduction: wave shuffle -> LDS -> one plain store per block ----
#pragma unroll
    for (int off = 32; off > 0; off >>= 1) lsum += __shfl_down(lsum, off, 64);
    if ((tid & 63) == 0) s_red[tid >> 6] = lsum;
    __syncthreads();
    if (tid == 0) {
        const int bid = (blockIdx.z * gridDim.y + blockIdx.y) * gridDim.x + blockIdx.x;
        partial[bid] = s_red[0] + s_red[1] + s_red[2] + s_red[3];
    }
}

extern "C" void kernel_launch(void* const* d_in, const int* in_sizes, int n_in,
                              void* d_out, int out_size, void* d_ws, size_t ws_size,
                              hipStream_t stream) {
    const float* img1 = (const float*)d_in[0];
    const float* img2 = (const float*)d_in[1];
    float* out = (float*)d_out;
    float* wsf = (float*)d_ws;   // 12288 partial sums (every slot written every launch)

    // Gaussian window, computed exactly as the reference (float64 -> float32)
    GW gw;
    {
        double g[11], s = 0.0;
        for (int i = 0; i < 11; ++i) {
            const double d = (double)(i - 5);
            g[i] = exp(-(d * d) / (2.0 * 1.5 * 1.5));
            s += g[i];
        }
        for (int i = 0; i < 11; ++i) gw.g[i] = (float)(g[i] / s);
    }

    dim3 grid(HWDIM / TILE, HWDIM / TILE, NPLANES);   // 16 x 16 x 48 = 12288
    ssim_main<<<grid, 256, 0, stream>>>(img1, img2, wsf, gw);
    ssim_reduce<<<1, 256, 0, stream>>>(wsf, out);
}